// Round 9
// baseline (230.869 us; speedup 1.0000x reference)
//
#include <hip/hip_runtime.h>
#include <hip/hip_fp16.h>
#include <math.h>

#define N_NODES 60000
#define N_EDGES 240000
#define F_INQ 10
#define G_DIM 512
#define NB_SCAN ((N_NODES + 255) / 256)   // 235
#define NB_EDGE ((N_EDGES + 255) / 256)   // 938

// ===========================================================================
// K_prep: fused degree histogram (blocks [0,NB_EDGE)) + graph-segment table
// (blocks [NB_EDGE, NB_EDGE+NB_SCAN)).
// ===========================================================================
__global__ __launch_bounds__(256) void k_prep(
    const int* __restrict__ ei, int* __restrict__ rs,
    const int* __restrict__ seg, int* __restrict__ gs)
{
    if (blockIdx.x < NB_EDGE) {
        int e = blockIdx.x * 256 + threadIdx.x;
        if (e < N_EDGES) atomicAdd(&rs[ei[e]], 1);
    } else {
        int i = (blockIdx.x - NB_EDGE) * 256 + threadIdx.x;
        if (i >= N_NODES) return;
        int s = seg[i];
        if (i == 0) { for (int g = 0; g <= s; ++g) gs[g] = 0; }
        else {
            int pr = seg[i - 1];
            for (int g = pr + 1; g <= s; ++g) gs[g] = i;
        }
        if (i == N_NODES - 1) { for (int g = s + 1; g <= G_DIM; ++g) gs[g] = N_NODES; }
    }
}

// ===========================================================================
// K_scan: per-block exclusive scan of rs + block totals; last block (ticket)
// exclusive-scans bsum in place. Global offset = rs[i] + bsum[i>>8].
// ===========================================================================
__global__ __launch_bounds__(256) void k_scan(
    int* __restrict__ rs, int* __restrict__ bsum, int* __restrict__ cnt)
{
    __shared__ int s[256];
    __shared__ int amLast;
    int i = blockIdx.x * 256 + threadIdx.x;
    int v = (i < N_NODES) ? rs[i] : 0;
    s[threadIdx.x] = v;
    __syncthreads();
    for (int off = 1; off < 256; off <<= 1) {
        int t = (threadIdx.x >= off) ? s[threadIdx.x - off] : 0;
        __syncthreads();
        s[threadIdx.x] += t;
        __syncthreads();
    }
    if (i < N_NODES) rs[i] = s[threadIdx.x] - v;  // block-local exclusive
    __syncthreads();
    if (threadIdx.x == 0) {
        bsum[blockIdx.x] = s[255];
        __threadfence();
        amLast = (atomicAdd(cnt, 1) == (int)gridDim.x - 1);
    }
    __syncthreads();
    if (!amLast) return;
    __threadfence();
    int b = (threadIdx.x < NB_SCAN) ? bsum[threadIdx.x] : 0;
    s[threadIdx.x] = b;
    __syncthreads();
    for (int off = 1; off < 256; off <<= 1) {
        int t = (threadIdx.x >= off) ? s[threadIdx.x - off] : 0;
        __syncthreads();
        s[threadIdx.x] += t;
        __syncthreads();
    }
    if (threadIdx.x < NB_SCAN) bsum[threadIdx.x] = s[threadIdx.x] - b;
}

__global__ __launch_bounds__(256) void k_fill(
    const int* __restrict__ ei, const float* __restrict__ a_vals,
    const float* __restrict__ efeat,
    int* __restrict__ rs, const int* __restrict__ bsum,
    int* __restrict__ ecol, float4* __restrict__ edata)
{
    int e = blockIdx.x * 256 + threadIdx.x;
    if (e >= N_EDGES) return;
    int row = ei[e];
    int slot = atomicAdd(&rs[row], 1) + bsum[row >> 8];
    ecol[slot] = ei[N_EDGES + e];
    edata[slot] = make_float4(a_vals[e], efeat[e * 3], efeat[e * 3 + 1], efeat[e * 3 + 2]);
}

// ---------------------------------------------------------------------------
// K_edge1: weight-free CSR reduction, layer 1. Lane = (node, f<10) PACKED.
// x is 2.4 MB fp32 -> fits per-XCD L2. PQ1[n,50] = [P0|P1|P2|P3|Q].
// ---------------------------------------------------------------------------
__global__ __launch_bounds__(256) void k_edge1(
    const float* __restrict__ x,
    const int* __restrict__ rs, const int* __restrict__ bsum,
    const int* __restrict__ ecol, const float4* __restrict__ edata,
    float* __restrict__ PQ1)
{
    int idx = blockIdx.x * 256 + threadIdx.x;
    if (idx >= N_NODES * F_INQ) return;
    int node = idx / F_INQ;
    int f = idx - node * F_INQ;
    int end = rs[node] + bsum[node >> 8];
    int start = (node == 0) ? 0 : (rs[node - 1] + bsum[(node - 1) >> 8]);
    float p0 = 0.f, p1 = 0.f, p2 = 0.f, p3 = 0.f, q = 0.f;
    for (int k = start; k < end; ++k) {
        int col = ecol[k];
        float4 ed = edata[k];
        float xv = x[col * F_INQ + f];
        p0 += xv;
        p1 += ed.y * xv;
        p2 += ed.z * xv;
        p3 += ed.w * xv;
        q  += ed.x * xv;
    }
    float* P = PQ1 + node * 50;
    P[f]      = p0;
    P[10 + f] = p1;
    P[20 + f] = p2;
    P[30 + f] = p3;
    P[40 + f] = q;
}

// ---------------------------------------------------------------------------
// K_tf1: per-node transform 1. Thread = (node, o<16), o fixed -> 60 weight
// floats in VGPRs, grid-stride. Output g1c1 as PACKED __half2(g,c):
// 3.84 MB total -> fits per-XCD L2 for edge2's random gather (the R9 fix).
// Precision: half eps ~5e-4 -> final output error ~3e-5 << 1.05e-2 threshold.
// ---------------------------------------------------------------------------
__global__ __launch_bounds__(256, 4) void k_tf1(
    const float* __restrict__ PQ1,
    const float* __restrict__ x,
    const float* __restrict__ Wg1,   // [10,16]
    const float* __restrict__ We1,   // [3,160]
    const float* __restrict__ be1,   // [160]
    const float* __restrict__ root1, // [10,16]
    const float* __restrict__ bias1, // [16]
    const float* __restrict__ bg1,   // [16]
    __half2* __restrict__ g1c1h)
{
    __shared__ float w[6 * 160 + 32];
    for (int t = threadIdx.x; t < 6 * 160 + 32; t += 256) {
        float v;
        if (t < 960) {
            int slot = t / 160, r = t - slot * 160;
            if (slot == 0)      v = Wg1[r];
            else if (slot <= 3) v = We1[(slot - 1) * 160 + r];
            else if (slot == 4) v = be1[r];
            else                v = root1[r];
        } else if (t < 976) v = bias1[t - 960];
        else                v = bg1[t - 976];
        w[t] = v;
    }
    __syncthreads();
    int o = threadIdx.x & 15;
    int ngrp = threadIdx.x >> 4;         // 0..15
    float wg[10], w0[10], w1[10], w2[10], bm[10], rt[10];
#pragma unroll
    for (int f = 0; f < 10; ++f) {
        wg[f] = w[f * 16 + o];
        w0[f] = w[160 + f * 16 + o];
        w1[f] = w[320 + f * 16 + o];
        w2[f] = w[480 + f * 16 + o];
        bm[f] = w[640 + f * 16 + o];
        rt[f] = w[800 + f * 16 + o];
    }
    float bia = w[960 + o], bgv = w[976 + o];
    for (int node = blockIdx.x * 16 + ngrp; node < N_NODES; node += gridDim.x * 16) {
        const float* P = PQ1 + node * 50;
        const float* xs = x + node * F_INQ;
        float ac = bia, ag = bgv;
#pragma unroll
        for (int f = 0; f < 10; ++f) {
            ac += P[f] * bm[f] + P[10 + f] * w0[f] + P[20 + f] * w1[f]
                + P[30 + f] * w2[f] + xs[f] * rt[f];
            ag += P[40 + f] * wg[f];
        }
        float gv = ag > 0.f ? ag : 0.f;
        float cv = ac > 0.f ? ac : 0.f;
        g1c1h[node * 16 + o] = __floats2half2_rn(gv, cv);
    }
}

// ---------------------------------------------------------------------------
// K_edge2: weight-free CSR reduction, layer 2. Lane = (node, f<16).
// One 4-B __half2 load per edge per lane: a 16-lane node-group reads exactly
// one 64 B line of the L2-resident 3.84 MB g1c1h. PQ2[n,80] fp32.
// ---------------------------------------------------------------------------
__global__ __launch_bounds__(256) void k_edge2(
    const __half2* __restrict__ g1c1h,
    const int* __restrict__ rs, const int* __restrict__ bsum,
    const int* __restrict__ ecol, const float4* __restrict__ edata,
    float* __restrict__ PQ2)
{
    int idx = blockIdx.x * 256 + threadIdx.x;   // 3750 blocks exact
    int node = idx >> 4, f = idx & 15;
    int end = rs[node] + bsum[node >> 8];
    int start = (node == 0) ? 0 : (rs[node - 1] + bsum[(node - 1) >> 8]);
    float p0 = 0.f, p1 = 0.f, p2 = 0.f, p3 = 0.f, q = 0.f;
    for (int k = start; k < end; ++k) {
        int col = ecol[k];
        float4 ed = edata[k];
        float2 gc = __half22float2(g1c1h[col * 16 + f]);
        p0 += gc.y;
        p1 += ed.y * gc.y;
        p2 += ed.z * gc.y;
        p3 += ed.w * gc.y;
        q  += ed.x * gc.x;
    }
    float* P = PQ2 + node * 80;
    P[f]      = p0;
    P[16 + f] = p1;
    P[32 + f] = p2;
    P[48 + f] = p3;
    P[64 + f] = q;
}

// ---------------------------------------------------------------------------
// K_tf2: per-node transform 2. Thread = (node, o<32), o fixed; 96 weight
// floats in VGPRs; grid-stride. c1-self read from packed g1c1h (.y).
// Output g2c2[n,64] = [g2(32)|c2(32)] fp32 (streamed, BW-cheap).
// ---------------------------------------------------------------------------
__global__ __launch_bounds__(256, 3) void k_tf2(
    const float* __restrict__ PQ2,
    const __half2* __restrict__ g1c1h,
    const float* __restrict__ Wg2,   // [16,32]
    const float* __restrict__ We2,   // [3,512]
    const float* __restrict__ be2,   // [512]
    const float* __restrict__ root2, // [16,32]
    const float* __restrict__ bias2, // [32]
    const float* __restrict__ bg2,   // [32]
    float* __restrict__ g2c2)
{
    __shared__ float w[6 * 512 + 64];
    for (int t = threadIdx.x; t < 6 * 512 + 64; t += 256) {
        float v;
        if (t < 3072) {
            int slot = t >> 9, r = t & 511;
            if (slot == 0)      v = Wg2[r];
            else if (slot <= 3) v = We2[(slot - 1) * 512 + r];
            else if (slot == 4) v = be2[r];
            else                v = root2[r];
        } else if (t < 3104) v = bias2[t - 3072];
        else                 v = bg2[t - 3104];
        w[t] = v;
    }
    __syncthreads();
    int o = threadIdx.x & 31;
    int ngrp = threadIdx.x >> 5;         // 0..7
    float wg[16], w0[16], w1[16], w2[16], bm[16], rt[16];
#pragma unroll
    for (int f = 0; f < 16; ++f) {
        wg[f] = w[f * 32 + o];
        w0[f] = w[512 + f * 32 + o];
        w1[f] = w[1024 + f * 32 + o];
        w2[f] = w[1536 + f * 32 + o];
        bm[f] = w[2048 + f * 32 + o];
        rt[f] = w[2560 + f * 32 + o];
    }
    float bia = w[3072 + o], bgv = w[3104 + o];
    for (int node = blockIdx.x * 8 + ngrp; node < N_NODES; node += gridDim.x * 8) {
        const float* P = PQ2 + node * 80;
        const __half2* cs = g1c1h + node * 16;
        float ac = bia, ag = bgv;
#pragma unroll
        for (int f = 0; f < 16; ++f) {
            float cv = __half22float2(cs[f]).y;
            ac += P[f] * bm[f] + P[16 + f] * w0[f] + P[32 + f] * w1[f]
                + P[48 + f] * w2[f] + cv * rt[f];
            ag += P[64 + f] * wg[f];
        }
        g2c2[node * 64 + o]      = ag > 0.f ? ag : 0.f;
        g2c2[node * 64 + 32 + o] = ac > 0.f ? ac : 0.f;
    }
}

// ---------------------------------------------------------------------------
// K_pool_head: one block per graph, 512 threads (8 waves — 2x the TLP of R8's
// 4-wave version; this kernel is a latency-bound streaming reduce at only
// 2 blocks/CU). Lane = channel j<64; LDS-reduce; fused MLP head.
// ---------------------------------------------------------------------------
__global__ __launch_bounds__(512) void k_pool_head(
    const float* __restrict__ g2c2,
    const int* __restrict__ gs,
    const float* __restrict__ Wd1, const float* __restrict__ bd1,
    const float* __restrict__ Wd2, const float* __restrict__ bd2,
    const float* __restrict__ Wo,  const float* __restrict__ bo,
    float* __restrict__ out)
{
    __shared__ float red[8][64];
    __shared__ float pl[64];
    __shared__ float h1s[16], h2s[8];
    int g = blockIdx.x;
    int s = gs[g], e = gs[g + 1];
    int wv = threadIdx.x >> 6, j = threadIdx.x & 63;
    float acc = 0.f;
    for (int nn = s + wv; nn < e; nn += 8)
        acc += g2c2[nn * 64 + j];
    red[wv][j] = acc;
    __syncthreads();
    if (wv == 0) {
        float a = red[0][j];
#pragma unroll
        for (int r = 1; r < 8; ++r) a += red[r][j];
        pl[j] = a;
    }
    __syncthreads();
    int t = threadIdx.x;
    if (t < 16) {
        float a = bd1[t];
        for (int k = 0; k < 64; ++k) a += pl[k] * Wd1[k * 16 + t];
        h1s[t] = a > 0.f ? a : 0.f;
    }
    __syncthreads();
    if (t < 8) {
        float a = bd2[t];
        for (int k = 0; k < 16; ++k) a += h1s[k] * Wd2[k * 8 + t];
        h2s[t] = a > 0.f ? a : 0.f;
    }
    __syncthreads();
    if (t == 0) {
        float a = bo[0];
        for (int k = 0; k < 8; ++k) a += h2s[k] * Wo[k];
        out[g] = 1.f / (1.f + expf(-a));
    }
}

// ---------------------------------------------------------------------------
// Workspace layout:
//   edata E*float4 | PQ1 N*50 f32 | g1c1h N*16 __half2 | PQ2 N*80 f32
//   | g2c2 N*64 f32 | rs[N] | cnt[1] | bsum[256] | gs[G+1] | ecol[E]
// 9 dispatches (memset + prep + scan + fill + edge1 + tf1 + edge2 + tf2 + pool).
// ---------------------------------------------------------------------------
extern "C" void kernel_launch(void* const* d_in, const int* in_sizes, int n_in,
                              void* d_out, int out_size, void* d_ws, size_t ws_size,
                              hipStream_t stream)
{
    const float* x      = (const float*)d_in[0];
    const float* a_vals = (const float*)d_in[1];
    const float* efeat  = (const float*)d_in[2];
    const int*   ei     = (const int*)d_in[3];
    const int*   seg    = (const int*)d_in[4];
    const float* Wg1    = (const float*)d_in[5];
    const float* bg1    = (const float*)d_in[6];
    const float* Wg2    = (const float*)d_in[7];
    const float* bg2    = (const float*)d_in[8];
    const float* We1    = (const float*)d_in[9];
    const float* be1    = (const float*)d_in[10];
    const float* root1  = (const float*)d_in[11];
    const float* bias1  = (const float*)d_in[12];
    const float* We2    = (const float*)d_in[13];
    const float* be2    = (const float*)d_in[14];
    const float* root2  = (const float*)d_in[15];
    const float* bias2  = (const float*)d_in[16];
    const float* Wd1    = (const float*)d_in[17];
    const float* bd1    = (const float*)d_in[18];
    const float* Wd2    = (const float*)d_in[19];
    const float* bd2    = (const float*)d_in[20];
    const float* Wo     = (const float*)d_in[21];
    const float* bo     = (const float*)d_in[22];

    float4*  edata = (float4*)d_ws;
    float*   PQ1   = (float*)(edata + N_EDGES);
    __half2* g1c1h = (__half2*)(PQ1 + (size_t)N_NODES * 50);
    float*   PQ2   = (float*)(g1c1h + (size_t)N_NODES * 16);
    float*   g2c2  = PQ2 + (size_t)N_NODES * 80;
    int*     rs    = (int*)(g2c2 + (size_t)N_NODES * 64);
    int*     cnt   = rs + N_NODES;
    int*     bsum  = cnt + 1;
    int*     gs    = bsum + 256;
    int*     ecol  = gs + (G_DIM + 1);
    float*   out   = (float*)d_out;

    hipMemsetAsync(rs, 0, sizeof(int) * (N_NODES + 1), stream);  // rs + cnt

    // CSR build + graph segments (3 dispatches)
    k_prep<<<NB_EDGE + NB_SCAN, 256, 0, stream>>>(ei, rs, seg, gs);
    k_scan<<<NB_SCAN, 256, 0, stream>>>(rs, bsum, cnt);
    k_fill<<<NB_EDGE, 256, 0, stream>>>(ei, a_vals, efeat, rs, bsum, ecol, edata);

    // Layer 1
    k_edge1<<<(N_NODES * F_INQ + 255) / 256, 256, 0, stream>>>(
        x, rs, bsum, ecol, edata, PQ1);
    k_tf1  <<<1280, 256, 0, stream>>>(PQ1, x, Wg1, We1, be1, root1, bias1, bg1, g1c1h);

    // Layer 2
    k_edge2<<<N_NODES * 16 / 256, 256, 0, stream>>>(g1c1h, rs, bsum, ecol, edata, PQ2);
    k_tf2  <<<1280, 256, 0, stream>>>(PQ2, g1c1h, Wg2, We2, be2, root2, bias2, bg2, g2c2);

    // Pool + MLP head
    k_pool_head<<<G_DIM, 512, 0, stream>>>(g2c2, gs, Wd1, bd1, Wd2, bd2, Wo, bo, out);
}